// Round 7
// baseline (260.432 us; speedup 1.0000x reference)
//
#include <hip/hip_runtime.h>
#include <hip/hip_bf16.h>

// GAT layer for MI355X (gfx950). FP32 in/out.
//   K0 gat_pack : adj (256 MB int32, values 0/1) -> 8 MB bitmask, read LINEARLY.
//     R2..R6 post-mortem: every schedule variant of the fused kernel pinned at
//     0.65-1.0 TB/s because the masked-GEMM access order (32 rows x 128B/step,
//     32KB row stride, chip-wide lockstep columns) thrashes DRAM pages /
//     aliases channels. A linear sweep (fillBuffer pattern) runs at ~87% peak.
//   K1 gat_wh   : Wh = h @ W^T via split-bf16 MFMA -> WhT_hi/lo[128][8192] bf16.
//   K2 gat_f12  : f1/f2 logits (fp32, pre-scaled by log2e).
//   K3 gat_flash: per-wave flash softmax+PV; mask byte (1B = 8 cols) replaces
//     the 32B adj fragment per lane -> HBM traffic ~0, bound by exp/MFMA/L2.

typedef __bf16 bf16;
typedef __attribute__((ext_vector_type(8))) __bf16 bf16x8;
typedef __attribute__((ext_vector_type(4))) float f32x4;

#define NN 8192
#define F_IN 256
#define F_OUT 128
#define LOG2E 1.44269504088896f
#define ALPHA 0.2f

// ---------------------------------------------------------------------------
// K0: pack adj -> mask words. mask32[row][tile] bit j = adj[row][tile*32+j]>0.
// Lane owns one 32-int tile (128B); 8 strided int4 loads, back-to-back, cover
// the wave's 8KB window densely; waves/blocks sweep 256 MB linearly.
// 2048 blocks x 256 thr x 4 words each = 2M words = 8 MB.
// ---------------------------------------------------------------------------
__global__ __launch_bounds__(256) void gat_pack(const int* __restrict__ adj,
                                                unsigned int* __restrict__ maskW) {
    const int gid = blockIdx.x * 256 + threadIdx.x;  // 0..524287
#pragma unroll
    for (int m = 0; m < 4; ++m) {
        const int T = m * 524288 + gid;
        const int4* p = (const int4*)(adj + (size_t)T * 32);
        unsigned int w = 0;
#pragma unroll
        for (int j = 0; j < 8; ++j) {
            const int4 v = p[j];
            w |= (v.x > 0 ? 1u : 0u) << (4 * j + 0);
            w |= (v.y > 0 ? 1u : 0u) << (4 * j + 1);
            w |= (v.z > 0 ? 1u : 0u) << (4 * j + 2);
            w |= (v.w > 0 ? 1u : 0u) << (4 * j + 3);
        }
        maskW[T] = w;
    }
}

__device__ __forceinline__ void split8(const float* __restrict__ p,
                                       bf16x8& hi, bf16x8& lo) {
    const float4 u = *(const float4*)p;
    const float4 v = *(const float4*)(p + 4);
    float f[8] = {u.x, u.y, u.z, u.w, v.x, v.y, v.z, v.w};
#pragma unroll
    for (int j = 0; j < 8; ++j) {
        const bf16 h = (bf16)f[j];
        hi[j] = h;
        lo[j] = (bf16)(f[j] - (float)h);
    }
}

// ---------------------------------------------------------------------------
// K1: Wh = h @ W^T (8192x128, K=256) -> transposed bf16 planes. (~3 us)
// ---------------------------------------------------------------------------
__global__ __launch_bounds__(128) void gat_wh(const float* __restrict__ h,
                                              const float* __restrict__ W,
                                              bf16* __restrict__ WhT_hi,
                                              bf16* __restrict__ WhT_lo) {
    const int tid = threadIdx.x;
    const int wv = tid >> 6;
    const int l15 = tid & 15;
    const int g = (tid & 63) >> 4;
    const int rowbase = blockIdx.x * 32 + wv * 16;

    f32x4 acc[8];
    const f32x4 zz = {0.f, 0.f, 0.f, 0.f};
#pragma unroll
    for (int nf = 0; nf < 8; ++nf) acc[nf] = zz;

#pragma unroll
    for (int ks = 0; ks < 8; ++ks) {
        const int k = ks * 32 + g * 8;
        bf16x8 ah, al;
        split8(h + (size_t)(rowbase + l15) * F_IN + k, ah, al);
#pragma unroll
        for (int nf = 0; nf < 8; ++nf) {
            bf16x8 bh, bl;
            split8(W + (size_t)(nf * 16 + l15) * F_IN + k, bh, bl);
            acc[nf] = __builtin_amdgcn_mfma_f32_16x16x32_bf16(ah, bh, acc[nf], 0, 0, 0);
            acc[nf] = __builtin_amdgcn_mfma_f32_16x16x32_bf16(ah, bl, acc[nf], 0, 0, 0);
            acc[nf] = __builtin_amdgcn_mfma_f32_16x16x32_bf16(al, bh, acc[nf], 0, 0, 0);
        }
    }

#pragma unroll
    for (int nf = 0; nf < 8; ++nf)
#pragma unroll
        for (int r = 0; r < 4; ++r) {
            const int row = rowbase + g * 4 + r;
            const int c = nf * 16 + l15;
            const float val = acc[nf][r];
            const bf16 vh = (bf16)val;
            WhT_hi[(size_t)c * NN + row] = vh;
            WhT_lo[(size_t)c * NN + row] = (bf16)(val - (float)vh);
        }
}

// ---------------------------------------------------------------------------
// K2: f1/f2 (fp32, pre-scaled by log2e). (~1 us)
// ---------------------------------------------------------------------------
__global__ __launch_bounds__(64) void gat_f12(const bf16* __restrict__ WhT_hi,
                                              const bf16* __restrict__ WhT_lo,
                                              const float* __restrict__ a,
                                              float* __restrict__ f1L,
                                              float* __restrict__ f2L) {
    const int i = blockIdx.x * 64 + threadIdx.x;
    float s1 = 0.f, s2 = 0.f;
#pragma unroll 8
    for (int c = 0; c < F_OUT; ++c) {
        const float wh = (float)WhT_hi[(size_t)c * NN + i] +
                         (float)WhT_lo[(size_t)c * NN + i];
        s1 += wh * a[c];
        s2 += wh * a[F_OUT + c];
    }
    f1L[i] = s1 * LOG2E;
    f2L[i] = s2 * LOG2E;
}

// ---------------------------------------------------------------------------
// K3: 256 blocks x 512 thr (8 waves = colh(2) x kq(4)), no main-loop barriers.
// Wave: rows [r0,r0+32), cols [64*colh,+64), k-slice 2048 (64 steps of 32).
// Lane (l15,g) step t: mask BYTE g of word (row, tile) = its 8 cols' bits.
// STEP(t): P(t) from mask bits -> 16 MFMAs; refill B/f2 <- t+2, mask <- t+4.
// ---------------------------------------------------------------------------
#define STEP(T, MA, MB, BH, BL, FA, FB)                                          \
    do {                                                                         \
        const float ff_[8] = {FA.x, FA.y, FA.z, FA.w, FB.x, FB.y, FB.z, FB.w};   \
        bf16x8 pa_, pb_;                                                         \
        _Pragma("unroll") for (int j = 0; j < 8; ++j) {                          \
            const float xa_ = f1a + ff_[j];                                      \
            const float xb_ = f1b + ff_[j];                                      \
            const float ea_ = __builtin_amdgcn_exp2f(fmaxf(xa_, ALPHA * xa_));   \
            const float eb_ = __builtin_amdgcn_exp2f(fmaxf(xb_, ALPHA * xb_));   \
            pa_[j] = (bf16)((MA & (1u << j)) ? ea_ : 0.f);                       \
            pb_[j] = (bf16)((MB & (1u << j)) ? eb_ : 0.f);                       \
        }                                                                        \
        _Pragma("unroll") for (int j = 0; j < 8; ++j) {                          \
            rsa += (float)pa_[j];                                                \
            rsb += (float)pb_[j];                                                \
        }                                                                        \
        _Pragma("unroll") for (int ct = 0; ct < 4; ++ct) {                       \
            accA[ct] = __builtin_amdgcn_mfma_f32_16x16x32_bf16(pa_, BH[ct], accA[ct], 0, 0, 0); \
            accA[ct] = __builtin_amdgcn_mfma_f32_16x16x32_bf16(pa_, BL[ct], accA[ct], 0, 0, 0); \
            accB[ct] = __builtin_amdgcn_mfma_f32_16x16x32_bf16(pb_, BH[ct], accB[ct], 0, 0, 0); \
            accB[ct] = __builtin_amdgcn_mfma_f32_16x16x32_bf16(pb_, BL[ct], accB[ct], 0, 0, 0); \
        }                                                                        \
        {                                                                        \
            const int k2_ = ((T) + 2 < 64 ? (T) + 2 : 63) * 32;                  \
            const int t4_ = ((T) + 4 < 64 ? (T) + 4 : 63) * 4;                   \
            _Pragma("unroll") for (int ct = 0; ct < 4; ++ct) {                   \
                BH[ct] = *(const bf16x8*)(bhp + (size_t)ct * 16 * NN + k2_);     \
                BL[ct] = *(const bf16x8*)(blp + (size_t)ct * 16 * NN + k2_);     \
            }                                                                    \
            FA = *(const float4*)(f2p + k2_);                                    \
            FB = *(const float4*)(f2p + k2_ + 4);                                \
            MA = mbA[t4_];                                                       \
            MB = mbB[t4_];                                                       \
        }                                                                        \
        __builtin_amdgcn_sched_barrier(0);                                       \
    } while (0)

__global__ __launch_bounds__(512, 2) void gat_flash(const unsigned char* __restrict__ maskB,
                                                    const bf16* __restrict__ WhT_hi,
                                                    const bf16* __restrict__ WhT_lo,
                                                    const float* __restrict__ f1L,
                                                    const float* __restrict__ f2L,
                                                    float* __restrict__ out) {
    __shared__ float accL[32][128];
    __shared__ float rsL[32];

    const int tid = threadIdx.x;
    const int wv = tid >> 6;   // 0..7
    const int kq = wv >> 1;    // 0..3 : k-slice of 2048
    const int colh = wv & 1;   // 0..1 : col half of 64
    const int l = tid & 63;
    const int l15 = l & 15;
    const int g = l >> 4;
    const int r0 = blockIdx.x * 32;

    const int kbase = kq * 2048;
    const float f1a = f1L[r0 + l15];
    const float f1b = f1L[r0 + 16 + l15];

    // mask: 1024 bytes per row; this wave's slice starts at byte kbase/8;
    // lane (l15,g) reads byte (t*4 + g) of the slice each step.
    const unsigned char* mbA = maskB + (size_t)(r0 + l15) * 1024 + (kbase >> 3) + g;
    const unsigned char* mbB = mbA + (size_t)16 * 1024;
    const float* f2p = f2L + kbase + g * 8;
    const bf16* bhp = WhT_hi + (size_t)(colh * 64 + l15) * NN + kbase + g * 8;
    const bf16* blp = WhT_lo + (size_t)(colh * 64 + l15) * NN + kbase + g * 8;

    f32x4 accA[4], accB[4];
    const f32x4 zz = {0.f, 0.f, 0.f, 0.f};
#pragma unroll
    for (int ct = 0; ct < 4; ++ct) { accA[ct] = zz; accB[ct] = zz; }
    float rsa = 0.f, rsb = 0.f;

    // ---- prologue: B/f2 for steps 0,1; mask bytes for steps 0..3 ----
    bf16x8 BH0[4], BL0[4], BH1[4], BL1[4];
#pragma unroll
    for (int ct = 0; ct < 4; ++ct) {
        BH0[ct] = *(const bf16x8*)(bhp + (size_t)ct * 16 * NN);
        BL0[ct] = *(const bf16x8*)(blp + (size_t)ct * 16 * NN);
        BH1[ct] = *(const bf16x8*)(bhp + (size_t)ct * 16 * NN + 32);
        BL1[ct] = *(const bf16x8*)(blp + (size_t)ct * 16 * NN + 32);
    }
    float4 f2a0 = *(const float4*)(f2p);
    float4 f2b0 = *(const float4*)(f2p + 4);
    float4 f2a1 = *(const float4*)(f2p + 32);
    float4 f2b1 = *(const float4*)(f2p + 36);

    unsigned int m0A = mbA[0], m0B = mbB[0];
    unsigned int m1A = mbA[4], m1B = mbB[4];
    unsigned int m2A = mbA[8], m2B = mbB[8];
    unsigned int m3A = mbA[12], m3B = mbB[12];
    __builtin_amdgcn_sched_barrier(0);

    for (int u = 0; u < 16; ++u) {
        const int t = u * 4;
        STEP(t + 0, m0A, m0B, BH0, BL0, f2a0, f2b0);
        STEP(t + 1, m1A, m1B, BH1, BL1, f2a1, f2b1);
        STEP(t + 2, m2A, m2B, BH0, BL0, f2a0, f2b0);
        STEP(t + 3, m3A, m3B, BH1, BL1, f2a1, f2b1);
    }

    // rowsum: combine the 4 g-groups (lanes with equal l15)
    rsa += __shfl_xor(rsa, 16);
    rsa += __shfl_xor(rsa, 32);
    rsb += __shfl_xor(rsb, 16);
    rsb += __shfl_xor(rsb, 32);

    // phased k-split reduction over kq. D layout: row=4*(l>>4)+reg, col=l&15.
    for (int ph = 0; ph < 4; ++ph) {
        if (kq == ph) {
            const int colb = colh * 64 + l15;
#pragma unroll
            for (int ct = 0; ct < 4; ++ct)
#pragma unroll
                for (int r = 0; r < 4; ++r) {
                    const int col = colb + ct * 16;
                    const int rowA = g * 4 + r;
                    const int rowB = 16 + g * 4 + r;
                    if (ph == 0) {
                        accL[rowA][col] = accA[ct][r];
                        accL[rowB][col] = accB[ct][r];
                    } else {
                        accL[rowA][col] += accA[ct][r];
                        accL[rowB][col] += accB[ct][r];
                    }
                }
            if (colh == 0 && l < 16) {
                if (ph == 0) {
                    rsL[l15] = rsa;
                    rsL[16 + l15] = rsb;
                } else {
                    rsL[l15] += rsa;
                    rsL[16 + l15] += rsb;
                }
            }
        }
        __syncthreads();
    }

    // divide + store: 512 thr x 8 floats = 32x128 tile
    const int row = tid >> 4;
    const int col = (tid & 15) * 8;
    const float inv = 1.0f / rsL[row];
    float4 v0 = *(const float4*)&accL[row][col];
    float4 v1 = *(const float4*)&accL[row][col + 4];
    v0.x *= inv; v0.y *= inv; v0.z *= inv; v0.w *= inv;
    v1.x *= inv; v1.y *= inv; v1.z *= inv; v1.w *= inv;
    *(float4*)(out + (size_t)(r0 + row) * F_OUT + col) = v0;
    *(float4*)(out + (size_t)(r0 + row) * F_OUT + col + 4) = v1;
}

// ---------------------------------------------------------------------------
extern "C" void kernel_launch(void* const* d_in, const int* in_sizes, int n_in,
                              void* d_out, int out_size, void* d_ws, size_t ws_size,
                              hipStream_t stream) {
    const float* h = (const float*)d_in[0];  // (8192, 256) fp32
    const int* adj = (const int*)d_in[1];    // (8192, 8192) int32
    const float* W = (const float*)d_in[2];  // (128, 256) fp32
    const float* a = (const float*)d_in[3];  // (1, 256) fp32
    float* out = (float*)d_out;              // (8192, 128) fp32

    char* ws = (char*)d_ws;
    bf16* WhT_hi = (bf16*)ws;                                    // 2 MB
    bf16* WhT_lo = (bf16*)(ws + (size_t)2 * 1024 * 1024);        // 2 MB
    float* f1L = (float*)(ws + (size_t)4 * 1024 * 1024);         // 32 KB
    float* f2L = f1L + NN;                                       // 32 KB
    unsigned int* maskW = (unsigned int*)(ws + (size_t)5 * 1024 * 1024);  // 8 MB

    gat_pack<<<2048, 256, 0, stream>>>(adj, maskW);
    gat_wh<<<256, 128, 0, stream>>>(h, W, WhT_hi, WhT_lo);
    gat_f12<<<NN / 64, 64, 0, stream>>>(WhT_hi, WhT_lo, a, f1L, f2L);
    gat_flash<<<NN / 32, 512, 0, stream>>>((const unsigned char*)maskW, WhT_hi, WhT_lo,
                                           f1L, f2L, out);
}

// Round 8
// 182.423 us; speedup vs baseline: 1.4276x; 1.4276x over previous
//
#include <hip/hip_runtime.h>
#include <hip/hip_bf16.h>

// GAT layer for MI355X (gfx950). FP32 in/out.
// R7 post-mortem: mask cut HBM fetch 150->20 MB yet flash stayed 167 us ->
// the invariant bottleneck is the HIDDEN 1 GB of WhT (B-operand) re-reads
// (256 blocks x 4 MB), served by L3 at ~6 TB/s. This round cuts B-traffic 8x:
//   grid = 32 row-tiles (256 rows) x 8 k-slices (1024 k); B per block 512 KB
//   staged through swizzled LDS chunks; fp32 k-partials + reduce kernel.
// Kernels: pack (linear adj->bitmask), wsplit (W hi/lo), wh (Wh GEMM),
//          f12 (logits), flash2 (masked softmax+PV partials), reduce.

typedef __bf16 bf16;
typedef __attribute__((ext_vector_type(8))) __bf16 bf16x8;
typedef __attribute__((ext_vector_type(4))) float f32x4;

#define NN 8192
#define F_IN 256
#define F_OUT 128
#define LOG2E 1.44269504088896f
#define ALPHA 0.2f
#define KSLICES 8
#define KSL 1024
#define RB 256

// ---------------------------------------------------------------------------
// K0: pack adj -> k-linear bitmask. Wave = one row (8192 waves); per round a
// lane reads 8 consecutive ints (2 x int4) and emits ONE mask byte (bit j =
// adj[row][8*byte+j] > 0); 64-lane byte store = 64B coalesced. Linear sweep.
// ---------------------------------------------------------------------------
__global__ __launch_bounds__(256) void gat_pack(const int* __restrict__ adj,
                                                unsigned char* __restrict__ maskB) {
    const int row = (blockIdx.x * 256 + threadIdx.x) >> 6;
    const int l = threadIdx.x & 63;
    const int* rowp = adj + (size_t)row * NN;
    unsigned char* outp = maskB + (size_t)row * 1024;
#pragma unroll 4
    for (int r = 0; r < 16; ++r) {
        const int base = r * 512 + l * 8;
        const int4 a = *(const int4*)(rowp + base);
        const int4 b = *(const int4*)(rowp + base + 4);
        unsigned int w = 0;
        w |= (a.x > 0) ? 1u : 0u;
        w |= (a.y > 0) ? 2u : 0u;
        w |= (a.z > 0) ? 4u : 0u;
        w |= (a.w > 0) ? 8u : 0u;
        w |= (b.x > 0) ? 16u : 0u;
        w |= (b.y > 0) ? 32u : 0u;
        w |= (b.z > 0) ? 64u : 0u;
        w |= (b.w > 0) ? 128u : 0u;
        outp[r * 64 + l] = (unsigned char)w;
    }
}

// ---------------------------------------------------------------------------
// K0b: split W (32768 fp32) into hi/lo bf16 planes ONCE (gat_wh was
// re-splitting W per block = 512x redundant VALU).
// ---------------------------------------------------------------------------
__global__ __launch_bounds__(256) void gat_wsplit(const float* __restrict__ W,
                                                  bf16* __restrict__ Whi,
                                                  bf16* __restrict__ Wlo) {
    const int i = blockIdx.x * 256 + threadIdx.x;
    const float v = W[i];
    const bf16 h = (bf16)v;
    Whi[i] = h;
    Wlo[i] = (bf16)(v - (float)h);
}

__device__ __forceinline__ void split8(const float* __restrict__ p,
                                       bf16x8& hi, bf16x8& lo) {
    const float4 u = *(const float4*)p;
    const float4 v = *(const float4*)(p + 4);
    float f[8] = {u.x, u.y, u.z, u.w, v.x, v.y, v.z, v.w};
#pragma unroll
    for (int j = 0; j < 8; ++j) {
        const bf16 h = (bf16)f[j];
        hi[j] = h;
        lo[j] = (bf16)(f[j] - (float)h);
    }
}

// ---------------------------------------------------------------------------
// K1: Wh = h @ W^T (8192x128, K=256) -> transposed bf16 planes WhT_hi/lo.
// ---------------------------------------------------------------------------
__global__ __launch_bounds__(128) void gat_wh(const float* __restrict__ h,
                                              const bf16* __restrict__ Whi,
                                              const bf16* __restrict__ Wlo,
                                              bf16* __restrict__ WhT_hi,
                                              bf16* __restrict__ WhT_lo) {
    const int tid = threadIdx.x;
    const int wv = tid >> 6;
    const int l15 = tid & 15;
    const int g = (tid & 63) >> 4;
    const int rowbase = blockIdx.x * 32 + wv * 16;

    f32x4 acc[8];
    const f32x4 zz = {0.f, 0.f, 0.f, 0.f};
#pragma unroll
    for (int nf = 0; nf < 8; ++nf) acc[nf] = zz;

#pragma unroll
    for (int ks = 0; ks < 8; ++ks) {
        const int k = ks * 32 + g * 8;
        bf16x8 ah, al;
        split8(h + (size_t)(rowbase + l15) * F_IN + k, ah, al);
#pragma unroll
        for (int nf = 0; nf < 8; ++nf) {
            const bf16x8 bh = *(const bf16x8*)(Whi + (size_t)(nf * 16 + l15) * F_IN + k);
            const bf16x8 bl = *(const bf16x8*)(Wlo + (size_t)(nf * 16 + l15) * F_IN + k);
            acc[nf] = __builtin_amdgcn_mfma_f32_16x16x32_bf16(ah, bh, acc[nf], 0, 0, 0);
            acc[nf] = __builtin_amdgcn_mfma_f32_16x16x32_bf16(ah, bl, acc[nf], 0, 0, 0);
            acc[nf] = __builtin_amdgcn_mfma_f32_16x16x32_bf16(al, bh, acc[nf], 0, 0, 0);
        }
    }

#pragma unroll
    for (int nf = 0; nf < 8; ++nf)
#pragma unroll
        for (int r = 0; r < 4; ++r) {
            const int row = rowbase + g * 4 + r;
            const int c = nf * 16 + l15;
            const float val = acc[nf][r];
            const bf16 vh = (bf16)val;
            WhT_hi[(size_t)c * NN + row] = vh;
            WhT_lo[(size_t)c * NN + row] = (bf16)(val - (float)vh);
        }
}

// ---------------------------------------------------------------------------
// K2: f1/f2 (fp32, pre-scaled by log2e).
// ---------------------------------------------------------------------------
__global__ __launch_bounds__(64) void gat_f12(const bf16* __restrict__ WhT_hi,
                                              const bf16* __restrict__ WhT_lo,
                                              const float* __restrict__ a,
                                              float* __restrict__ f1L,
                                              float* __restrict__ f2L) {
    const int i = blockIdx.x * 64 + threadIdx.x;
    float s1 = 0.f, s2 = 0.f;
#pragma unroll 8
    for (int c = 0; c < F_OUT; ++c) {
        const float wh = (float)WhT_hi[(size_t)c * NN + i] +
                         (float)WhT_lo[(size_t)c * NN + i];
        s1 += wh * a[c];
        s2 += wh * a[F_OUT + c];
    }
    f1L[i] = s1 * LOG2E;
    f2L[i] = s2 * LOG2E;
}

// ---------------------------------------------------------------------------
// K3: flash2. Grid 256 = 32 row-tiles x 8 k-slices (blockIdx&7 = ks -> same
// slice lands on one XCD; its 512 KB B-slice stays L2-hot). 512 thr, 8 waves;
// wave = 32 rows x 128 cols x 1024 k. Per 256-k chunk: stage B hi/lo into
// swizzled LDS (128 KB), then 8 barrier-free steps of {mask byte + f2 + exp ->
// P frags; 16 ds_read_b128; 32 MFMA}. fp32 partials out (k-split reduction
// done by gat_reduce; no atomics -> deterministic).
// ---------------------------------------------------------------------------
__global__ __launch_bounds__(512, 2) void gat_flash2(
        const unsigned char* __restrict__ maskB,
        const bf16* __restrict__ WhT_hi,
        const bf16* __restrict__ WhT_lo,
        const float* __restrict__ f1L,
        const float* __restrict__ f2L,
        float* __restrict__ O_part,
        float* __restrict__ rs_part) {
    __shared__ bf16 Blds[2 * 128 * 256];  // 128 KB, [plane][c][256k], swizzled

    const int tid = threadIdx.x;
    const int wv = tid >> 6;
    const int l = tid & 63;
    const int l15 = l & 15;
    const int g = l >> 4;
    const int rb = blockIdx.x >> 3;
    const int ks = blockIdx.x & 7;
    const int row0 = rb * RB + wv * 32;

    const float f1a = f1L[row0 + l15];
    const float f1b = f1L[row0 + 16 + l15];
    const unsigned char* mb0 = maskB + (size_t)(row0 + l15) * 1024 + ks * 128 + g;
    const unsigned char* mb1 = mb0 + (size_t)16 * 1024;
    const float* f2p = f2L + ks * KSL + g * 8;

    f32x4 acc[2][8];
    const f32x4 zz = {0.f, 0.f, 0.f, 0.f};
#pragma unroll
    for (int m = 0; m < 2; ++m)
#pragma unroll
        for (int nf = 0; nf < 8; ++nf) acc[m][nf] = zz;
    float rs0 = 0.f, rs1 = 0.f;

    char* ldsb = (char*)&Blds[0];

    for (int c4 = 0; c4 < 4; ++c4) {
        const int kc0 = ks * KSL + c4 * 256;  // chunk's global k start
        // ---- stage B chunk (2 planes x 128 c x 256 k) into swizzled LDS ----
#pragma unroll
        for (int it = 0; it < 16; ++it) {
            const int idx = it * 512 + tid;
            const int p = idx >> 12;          // plane (uniform per it-pair)
            const int cc = (idx >> 5) & 127;  // col
            const int kc = idx & 31;          // 16B unit within chunk
            const bf16* src = (p ? WhT_lo : WhT_hi) + (size_t)cc * NN + kc0 + kc * 8;
            const bf16x8 v = *(const bf16x8*)src;
            const int dst = (p << 16) + cc * 512 + kc * 16;
            *(bf16x8*)(ldsb + (dst ^ ((cc & 7) << 4))) = v;
        }
        __syncthreads();

        // ---- 8 barrier-free k-steps ----
#pragma unroll
        for (int s = 0; s < 8; ++s) {
            const int t = c4 * 8 + s;
            const unsigned int ma = mb0[t * 4];
            const unsigned int mbv = mb1[t * 4];
            const float4 fa = *(const float4*)(f2p + t * 32);
            const float4 fb = *(const float4*)(f2p + t * 32 + 4);
            const float ff[8] = {fa.x, fa.y, fa.z, fa.w, fb.x, fb.y, fb.z, fb.w};

            bf16x8 pa, pb;
#pragma unroll
            for (int j = 0; j < 8; ++j) {
                const float xa = f1a + ff[j];
                const float xb = f1b + ff[j];
                const float ea = __builtin_amdgcn_exp2f(fmaxf(xa, ALPHA * xa));
                const float eb = __builtin_amdgcn_exp2f(fmaxf(xb, ALPHA * xb));
                pa[j] = (bf16)((ma & (1u << j)) ? ea : 0.f);
                pb[j] = (bf16)((mbv & (1u << j)) ? eb : 0.f);
            }
#pragma unroll
            for (int j = 0; j < 8; ++j) {
                rs0 += (float)pa[j];
                rs1 += (float)pb[j];
            }

#pragma unroll
            for (int nf = 0; nf < 8; ++nf) {
                const int c = nf * 16 + l15;
                const int off = c * 512 + s * 64 + g * 16;
                const int sw = (c & 7) << 4;
                const bf16x8 bh = *(const bf16x8*)(ldsb + (off ^ sw));
                const bf16x8 bl = *(const bf16x8*)(ldsb + ((off + 65536) ^ sw));
                acc[0][nf] = __builtin_amdgcn_mfma_f32_16x16x32_bf16(pa, bh, acc[0][nf], 0, 0, 0);
                acc[0][nf] = __builtin_amdgcn_mfma_f32_16x16x32_bf16(pa, bl, acc[0][nf], 0, 0, 0);
                acc[1][nf] = __builtin_amdgcn_mfma_f32_16x16x32_bf16(pb, bh, acc[1][nf], 0, 0, 0);
                acc[1][nf] = __builtin_amdgcn_mfma_f32_16x16x32_bf16(pb, bl, acc[1][nf], 0, 0, 0);
            }
        }
        __syncthreads();
    }

    // rowsum partials: combine g-groups; lanes 0..15 write 32 rows
    rs0 += __shfl_xor(rs0, 16);
    rs0 += __shfl_xor(rs0, 32);
    rs1 += __shfl_xor(rs1, 16);
    rs1 += __shfl_xor(rs1, 32);
    if (l < 16) {
        rs_part[(size_t)ks * NN + row0 + l15] = rs0;
        rs_part[(size_t)ks * NN + row0 + 16 + l15] = rs1;
    }

    // O partials. D layout (m89): row-in-frag = 4*(l>>4)+reg, col = l&15.
    float* ob = O_part + ((size_t)ks << 20);
#pragma unroll
    for (int m = 0; m < 2; ++m)
#pragma unroll
        for (int nf = 0; nf < 8; ++nf)
#pragma unroll
            for (int r = 0; r < 4; ++r) {
                const int row = row0 + m * 16 + g * 4 + r;
                const int col = nf * 16 + l15;
                ob[(size_t)row * F_OUT + col] = acc[m][nf][r];
            }
}

// ---------------------------------------------------------------------------
// K4: reduce k-slices: out = (sum_s O_part[s]) / (sum_s rs_part[s]).
// ---------------------------------------------------------------------------
__global__ __launch_bounds__(256) void gat_reduce(const float* __restrict__ O_part,
                                                  const float* __restrict__ rs_part,
                                                  float* __restrict__ out) {
    const int idx = blockIdx.x * 256 + threadIdx.x;  // one float4 each
    const int r = idx >> 5;
    const int c = (idx & 31) * 4;
    float rsum = 0.f;
#pragma unroll
    for (int s = 0; s < KSLICES; ++s) rsum += rs_part[(size_t)s * NN + r];
    float4 o = {0.f, 0.f, 0.f, 0.f};
#pragma unroll
    for (int s = 0; s < KSLICES; ++s) {
        const float4 v = *(const float4*)(O_part + ((size_t)s << 20) + (size_t)r * F_OUT + c);
        o.x += v.x;
        o.y += v.y;
        o.z += v.z;
        o.w += v.w;
    }
    const float inv = 1.0f / rsum;
    o.x *= inv;
    o.y *= inv;
    o.z *= inv;
    o.w *= inv;
    *(float4*)(out + (size_t)r * F_OUT + c) = o;
}

// ---------------------------------------------------------------------------
extern "C" void kernel_launch(void* const* d_in, const int* in_sizes, int n_in,
                              void* d_out, int out_size, void* d_ws, size_t ws_size,
                              hipStream_t stream) {
    const float* h = (const float*)d_in[0];  // (8192, 256) fp32
    const int* adj = (const int*)d_in[1];    // (8192, 8192) int32
    const float* W = (const float*)d_in[2];  // (128, 256) fp32
    const float* a = (const float*)d_in[3];  // (1, 256) fp32
    float* out = (float*)d_out;              // (8192, 128) fp32

    char* ws = (char*)d_ws;
    const size_t MB = 1024 * 1024;
    bf16* WhT_hi = (bf16*)ws;                               // 2 MB
    bf16* WhT_lo = (bf16*)(ws + 2 * MB);                    // 2 MB
    float* f1L = (float*)(ws + 4 * MB);                     // 32 KB
    float* f2L = f1L + NN;                                  // 32 KB
    bf16* Whi = (bf16*)(ws + 4 * MB + 64 * 1024);           // 64 KB
    bf16* Wlo = (bf16*)(ws + 4 * MB + 128 * 1024);          // 64 KB
    unsigned char* maskB = (unsigned char*)(ws + 5 * MB);   // 8 MB
    float* rs_part = (float*)(ws + 13 * MB);                // 256 KB
    float* O_part = (float*)(ws + 14 * MB);                 // 32 MB

    gat_pack<<<2048, 256, 0, stream>>>(adj, maskB);
    gat_wsplit<<<128, 256, 0, stream>>>(W, Whi, Wlo);
    gat_wh<<<256, 128, 0, stream>>>(h, Whi, Wlo, WhT_hi, WhT_lo);
    gat_f12<<<NN / 64, 64, 0, stream>>>(WhT_hi, WhT_lo, a, f1L, f2L);
    gat_flash2<<<256, 512, 0, stream>>>(maskB, WhT_hi, WhT_lo, f1L, f2L, O_part, rs_part);
    gat_reduce<<<NN * F_OUT / 4 / 256, 256, 0, stream>>>(O_part, rs_part, out);
}

// Round 9
// 174.402 us; speedup vs baseline: 1.4933x; 1.0460x over previous
//
#include <hip/hip_runtime.h>
#include <hip/hip_bf16.h>

// GAT layer for MI355X (gfx950). FP32 in/out.
// R8 post-mortem: flash2's MFMA floor (34.4 GFLOP incl. lo-plane) + pack are
// the remaining elephants. R9: (1) PV uses SINGLE bf16 B plane (halves MFMA,
// LDS chunk 64 KB -> 2 blocks/CU, 4 waves/SIMD, setprio on MFMA); error
// analysis: p-weighted avg of independent +-2^-9|Wh| roundings mostly cancels.
// (2) pack via __ballot: 256 B/inst dense loads, 1 wave-inst per 64 mask bits.
// Kernels: pack, wsplit, wh (split-bf16 GEMM, bf16 out), f12, flash3, reduce.

typedef __bf16 bf16;
typedef __attribute__((ext_vector_type(8))) __bf16 bf16x8;
typedef __attribute__((ext_vector_type(4))) float f32x4;

#define NN 8192
#define F_IN 256
#define F_OUT 128
#define LOG2E 1.44269504088896f
#define ALPHA 0.2f
#define KSLICES 8

// ---------------------------------------------------------------------------
// K0: pack adj -> bitmask via ballot. Wave = one row; round a: lane l reads
// adj[row][64a+l] (256 B contiguous per inst), ballot(v>0) = 64-bit word,
// lane 0 stores. 8192 waves, pure linear HBM stream.
// ---------------------------------------------------------------------------
__global__ __launch_bounds__(256) void gat_pack(const int* __restrict__ adj,
                                                unsigned long long* __restrict__ maskU) {
    const int row = (blockIdx.x * 256 + threadIdx.x) >> 6;
    const int l = threadIdx.x & 63;
    const int* rowp = adj + (size_t)row * NN;
    unsigned long long* outp = maskU + (size_t)row * 128;
#pragma unroll 4
    for (int a = 0; a < 128; ++a) {
        const int v = rowp[a * 64 + l];
        const unsigned long long bal = __ballot(v > 0);
        if (l == 0) outp[a] = bal;
    }
}

// ---------------------------------------------------------------------------
// K0b: split W into hi/lo bf16 planes once (for the accurate Wh GEMM).
// ---------------------------------------------------------------------------
__global__ __launch_bounds__(256) void gat_wsplit(const float* __restrict__ W,
                                                  bf16* __restrict__ Whi,
                                                  bf16* __restrict__ Wlo) {
    const int i = blockIdx.x * 256 + threadIdx.x;
    const float v = W[i];
    const bf16 h = (bf16)v;
    Whi[i] = h;
    Wlo[i] = (bf16)(v - (float)h);
}

__device__ __forceinline__ void split8(const float* __restrict__ p,
                                       bf16x8& hi, bf16x8& lo) {
    const float4 u = *(const float4*)p;
    const float4 v = *(const float4*)(p + 4);
    float f[8] = {u.x, u.y, u.z, u.w, v.x, v.y, v.z, v.w};
#pragma unroll
    for (int j = 0; j < 8; ++j) {
        const bf16 h = (bf16)f[j];
        hi[j] = h;
        lo[j] = (bf16)(f[j] - (float)h);
    }
}

// ---------------------------------------------------------------------------
// K1: Wh = h @ W^T (8192x128, K=256), split-bf16 accurate, -> WhT bf16 [128][8192].
// ---------------------------------------------------------------------------
__global__ __launch_bounds__(128) void gat_wh(const float* __restrict__ h,
                                              const bf16* __restrict__ Whi,
                                              const bf16* __restrict__ Wlo,
                                              bf16* __restrict__ WhT) {
    const int tid = threadIdx.x;
    const int wv = tid >> 6;
    const int l15 = tid & 15;
    const int g = (tid & 63) >> 4;
    const int rowbase = blockIdx.x * 32 + wv * 16;

    f32x4 acc[8];
    const f32x4 zz = {0.f, 0.f, 0.f, 0.f};
#pragma unroll
    for (int nf = 0; nf < 8; ++nf) acc[nf] = zz;

#pragma unroll
    for (int ks = 0; ks < 8; ++ks) {
        const int k = ks * 32 + g * 8;
        bf16x8 ah, al;
        split8(h + (size_t)(rowbase + l15) * F_IN + k, ah, al);
#pragma unroll
        for (int nf = 0; nf < 8; ++nf) {
            const bf16x8 bh = *(const bf16x8*)(Whi + (size_t)(nf * 16 + l15) * F_IN + k);
            const bf16x8 bl = *(const bf16x8*)(Wlo + (size_t)(nf * 16 + l15) * F_IN + k);
            acc[nf] = __builtin_amdgcn_mfma_f32_16x16x32_bf16(ah, bh, acc[nf], 0, 0, 0);
            acc[nf] = __builtin_amdgcn_mfma_f32_16x16x32_bf16(ah, bl, acc[nf], 0, 0, 0);
            acc[nf] = __builtin_amdgcn_mfma_f32_16x16x32_bf16(al, bh, acc[nf], 0, 0, 0);
        }
    }

#pragma unroll
    for (int nf = 0; nf < 8; ++nf)
#pragma unroll
        for (int r = 0; r < 4; ++r) {
            const int row = rowbase + g * 4 + r;
            const int c = nf * 16 + l15;
            WhT[(size_t)c * NN + row] = (bf16)acc[nf][r];
        }
}

// ---------------------------------------------------------------------------
// K2: f1/f2 (fp32, pre-scaled by log2e), from bf16 WhT (error ~1e-3, fine).
// ---------------------------------------------------------------------------
__global__ __launch_bounds__(64) void gat_f12(const bf16* __restrict__ WhT,
                                              const float* __restrict__ a,
                                              float* __restrict__ f1L,
                                              float* __restrict__ f2L) {
    const int i = blockIdx.x * 64 + threadIdx.x;
    float s1 = 0.f, s2 = 0.f;
#pragma unroll 8
    for (int c = 0; c < F_OUT; ++c) {
        const float wh = (float)WhT[(size_t)c * NN + i];
        s1 += wh * a[c];
        s2 += wh * a[F_OUT + c];
    }
    f1L[i] = s1 * LOG2E;
    f2L[i] = s2 * LOG2E;
}

// ---------------------------------------------------------------------------
// K3: flash3. Grid 512 = 64 row-tiles(128 rows) x 8 k-slices(1024 k).
// 512 thr, 8 waves; wave = 16 rows x 128 cols x 1024 k. LDS = one 64 KB B
// chunk [128c][256k] (swizzled) -> 2 blocks/CU, 4 waves/SIMD. Per step (k=32):
// mask byte + 8 exps -> pa; setprio(1); 8 ds_read_b128 + 8 MFMA; setprio(0).
// fp32 partials per (rt,ks); gat_reduce combines (deterministic).
// ---------------------------------------------------------------------------
__global__ __launch_bounds__(512, 4) void gat_flash3(
        const unsigned char* __restrict__ maskB,
        const bf16* __restrict__ WhT,
        const float* __restrict__ f1L,
        const float* __restrict__ f2L,
        float* __restrict__ O_part,
        float* __restrict__ rs_part) {
    __shared__ bf16 Blds[128 * 256];  // 64 KB

    const int tid = threadIdx.x;
    const int wv = tid >> 6;
    const int l = tid & 63;
    const int l15 = l & 15;
    const int g = l >> 4;
    const int rb = blockIdx.x >> 3;  // 0..63
    const int ks = blockIdx.x & 7;   // 0..7
    const int row0 = rb * 128 + wv * 16;

    const float f1a = f1L[row0 + l15];
    const unsigned char* mb0 = maskB + (size_t)(row0 + l15) * 1024 + ks * 128 + g;
    const float* f2p = f2L + ks * 1024 + g * 8;

    f32x4 acc[8];
    const f32x4 zz = {0.f, 0.f, 0.f, 0.f};
#pragma unroll
    for (int nf = 0; nf < 8; ++nf) acc[nf] = zz;
    float rs0 = 0.f;

    char* ldsb = (char*)&Blds[0];

    for (int c4 = 0; c4 < 4; ++c4) {
        const int kc0 = ks * 1024 + c4 * 256;
        // ---- stage B chunk: 128 c x 256 k bf16, XOR-swizzled ----
#pragma unroll
        for (int it = 0; it < 8; ++it) {
            const int idx = it * 512 + tid;   // 0..4095 16B-units
            const int cc = idx >> 5;          // col 0..127
            const int ku = idx & 31;          // 16B unit in k
            const bf16x8 v = *(const bf16x8*)(WhT + (size_t)cc * NN + kc0 + ku * 8);
            const int dst = cc * 512 + ku * 16;
            *(bf16x8*)(ldsb + (dst ^ ((cc & 7) << 4))) = v;
        }
        __syncthreads();

#pragma unroll
        for (int s = 0; s < 8; ++s) {
            const int t = c4 * 8 + s;
            const unsigned int ma = mb0[t * 4];
            const float4 fa = *(const float4*)(f2p + t * 32);
            const float4 fb = *(const float4*)(f2p + t * 32 + 4);
            const float ff[8] = {fa.x, fa.y, fa.z, fa.w, fb.x, fb.y, fb.z, fb.w};

            bf16x8 pa;
#pragma unroll
            for (int j = 0; j < 8; ++j) {
                const float xa = f1a + ff[j];
                const float ea = __builtin_amdgcn_exp2f(fmaxf(xa, ALPHA * xa));
                pa[j] = (bf16)((ma & (1u << j)) ? ea : 0.f);
            }
#pragma unroll
            for (int j = 0; j < 8; ++j) rs0 += (float)pa[j];

            __builtin_amdgcn_s_setprio(1);
#pragma unroll
            for (int nf = 0; nf < 8; ++nf) {
                const int c = nf * 16 + l15;
                const int off = c * 512 + s * 64 + g * 16;
                const bf16x8 bh = *(const bf16x8*)(ldsb + (off ^ ((c & 7) << 4)));
                acc[nf] = __builtin_amdgcn_mfma_f32_16x16x32_bf16(pa, bh, acc[nf], 0, 0, 0);
            }
            __builtin_amdgcn_s_setprio(0);
        }
        __syncthreads();
    }

    // rowsum partial: combine the 4 g-groups (lanes with equal l15)
    rs0 += __shfl_xor(rs0, 16);
    rs0 += __shfl_xor(rs0, 32);
    if (l < 16) rs_part[(size_t)ks * NN + row0 + l15] = rs0;

    // O partial. D layout (m89): row = 4*(l>>4)+reg, col = l&15.
    float* ob = O_part + ((size_t)ks << 20);
#pragma unroll
    for (int nf = 0; nf < 8; ++nf)
#pragma unroll
        for (int r = 0; r < 4; ++r)
            ob[(size_t)(row0 + g * 4 + r) * F_OUT + nf * 16 + l15] = acc[nf][r];
}

// ---------------------------------------------------------------------------
// K4: reduce k-slices: out = (sum_s O_part[s]) / (sum_s rs_part[s]).
// ---------------------------------------------------------------------------
__global__ __launch_bounds__(256) void gat_reduce(const float* __restrict__ O_part,
                                                  const float* __restrict__ rs_part,
                                                  float* __restrict__ out) {
    const int idx = blockIdx.x * 256 + threadIdx.x;
    const int r = idx >> 5;
    const int c = (idx & 31) * 4;
    float rsum = 0.f;
#pragma unroll
    for (int s = 0; s < KSLICES; ++s) rsum += rs_part[(size_t)s * NN + r];
    float4 o = {0.f, 0.f, 0.f, 0.f};
#pragma unroll
    for (int s = 0; s < KSLICES; ++s) {
        const float4 v = *(const float4*)(O_part + ((size_t)s << 20) + (size_t)r * F_OUT + c);
        o.x += v.x;
        o.y += v.y;
        o.z += v.z;
        o.w += v.w;
    }
    const float inv = 1.0f / rsum;
    o.x *= inv;
    o.y *= inv;
    o.z *= inv;
    o.w *= inv;
    *(float4*)(out + (size_t)r * F_OUT + c) = o;
}

// ---------------------------------------------------------------------------
extern "C" void kernel_launch(void* const* d_in, const int* in_sizes, int n_in,
                              void* d_out, int out_size, void* d_ws, size_t ws_size,
                              hipStream_t stream) {
    const float* h = (const float*)d_in[0];  // (8192, 256) fp32
    const int* adj = (const int*)d_in[1];    // (8192, 8192) int32
    const float* W = (const float*)d_in[2];  // (128, 256) fp32
    const float* a = (const float*)d_in[3];  // (1, 256) fp32
    float* out = (float*)d_out;              // (8192, 128) fp32

    char* ws = (char*)d_ws;
    const size_t MB = 1024 * 1024;
    bf16* WhT = (bf16*)ws;                                  // 2 MB
    float* f1L = (float*)(ws + 2 * MB);                     // 32 KB
    float* f2L = f1L + NN;                                  // 32 KB
    bf16* Whi = (bf16*)(ws + 2 * MB + 64 * 1024);           // 64 KB
    bf16* Wlo = (bf16*)(ws + 2 * MB + 128 * 1024);          // 64 KB
    unsigned long long* maskU = (unsigned long long*)(ws + 3 * MB);  // 8 MB
    float* rs_part = (float*)(ws + 11 * MB);                // 256 KB
    float* O_part = (float*)(ws + 12 * MB);                 // 32 MB

    gat_pack<<<2048, 256, 0, stream>>>(adj, maskU);
    gat_wsplit<<<128, 256, 0, stream>>>(W, Whi, Wlo);
    gat_wh<<<256, 128, 0, stream>>>(h, Whi, Wlo, WhT);
    gat_f12<<<NN / 64, 64, 0, stream>>>(WhT, a, f1L, f2L);
    gat_flash3<<<512, 512, 0, stream>>>((const unsigned char*)maskU, WhT, f1L, f2L,
                                        O_part, rs_part);
    gat_reduce<<<NN * F_OUT / 4 / 256, 256, 0, stream>>>(O_part, rs_part, out);
}

// Round 10
// 150.852 us; speedup vs baseline: 1.7264x; 1.1561x over previous
//
#include <hip/hip_runtime.h>
#include <hip/hip_bf16.h>

// GAT layer for MI355X (gfx950). FP32 in/out.
// R9 post-mortem: with B staged via LDS (R8/R9), the 1 GB WhT L3 stream that
// made direct adj reads crawl (R2-R7) is gone -> fuse adj back into flash and
// drop the pack kernel + mask round-trip. adj (256 MB) is read ONCE in MFMA
// A-frag layout (full 128B line utilization), 2-step static-parity prefetch.
// f12 folded into wh (fp32-acc shuffle reduce). 4 dispatches:
//   wsplit -> wh(+f12) -> flash4 -> reduce.

typedef __bf16 bf16;
typedef __attribute__((ext_vector_type(8))) __bf16 bf16x8;
typedef __attribute__((ext_vector_type(4))) float f32x4;

#define NN 8192
#define F_IN 256
#define F_OUT 128
#define LOG2E 1.44269504088896f
#define ALPHA 0.2f
#define KSLICES 8

// ---------------------------------------------------------------------------
// K0: split W into hi/lo bf16 planes once.
// ---------------------------------------------------------------------------
__global__ __launch_bounds__(256) void gat_wsplit(const float* __restrict__ W,
                                                  bf16* __restrict__ Whi,
                                                  bf16* __restrict__ Wlo) {
    const int i = blockIdx.x * 256 + threadIdx.x;
    const float v = W[i];
    const bf16 h = (bf16)v;
    Whi[i] = h;
    Wlo[i] = (bf16)(v - (float)h);
}

__device__ __forceinline__ void split8(const float* __restrict__ p,
                                       bf16x8& hi, bf16x8& lo) {
    const float4 u = *(const float4*)p;
    const float4 v = *(const float4*)(p + 4);
    float f[8] = {u.x, u.y, u.z, u.w, v.x, v.y, v.z, v.w};
#pragma unroll
    for (int j = 0; j < 8; ++j) {
        const bf16 h = (bf16)f[j];
        hi[j] = h;
        lo[j] = (bf16)(f[j] - (float)h);
    }
}

// ---------------------------------------------------------------------------
// K1: Wh = h @ W^T (split-bf16, fp32 acc) -> WhT bf16 [128][8192]; f1/f2
// computed IN-BLOCK from the fp32 acc (16-lane shuffle reduce), pre-scaled.
// 256 blocks x 128 thr (2 waves x 16 rows).
// ---------------------------------------------------------------------------
__global__ __launch_bounds__(128) void gat_wh(const float* __restrict__ h,
                                              const bf16* __restrict__ Whi,
                                              const bf16* __restrict__ Wlo,
                                              const float* __restrict__ a,
                                              bf16* __restrict__ WhT,
                                              float* __restrict__ f1L,
                                              float* __restrict__ f2L) {
    const int tid = threadIdx.x;
    const int wv = tid >> 6;
    const int l15 = tid & 15;
    const int g = (tid & 63) >> 4;
    const int rowbase = blockIdx.x * 32 + wv * 16;

    f32x4 acc[8];
    const f32x4 zz = {0.f, 0.f, 0.f, 0.f};
#pragma unroll
    for (int nf = 0; nf < 8; ++nf) acc[nf] = zz;

#pragma unroll
    for (int ks = 0; ks < 8; ++ks) {
        const int k = ks * 32 + g * 8;
        bf16x8 ah, al;
        split8(h + (size_t)(rowbase + l15) * F_IN + k, ah, al);
#pragma unroll
        for (int nf = 0; nf < 8; ++nf) {
            const bf16x8 bh = *(const bf16x8*)(Whi + (size_t)(nf * 16 + l15) * F_IN + k);
            const bf16x8 bl = *(const bf16x8*)(Wlo + (size_t)(nf * 16 + l15) * F_IN + k);
            acc[nf] = __builtin_amdgcn_mfma_f32_16x16x32_bf16(ah, bh, acc[nf], 0, 0, 0);
            acc[nf] = __builtin_amdgcn_mfma_f32_16x16x32_bf16(ah, bl, acc[nf], 0, 0, 0);
            acc[nf] = __builtin_amdgcn_mfma_f32_16x16x32_bf16(al, bh, acc[nf], 0, 0, 0);
        }
    }

    // WhT stores (transposed, bf16)
#pragma unroll
    for (int nf = 0; nf < 8; ++nf)
#pragma unroll
        for (int r = 0; r < 4; ++r)
            WhT[(size_t)(nf * 16 + l15) * NN + rowbase + g * 4 + r] = (bf16)acc[nf][r];

    // f1/f2 from fp32 acc: lane owns cols nf*16+l15 for rows rowbase+g*4+r.
    float a1c[8], a2c[8];
#pragma unroll
    for (int nf = 0; nf < 8; ++nf) {
        a1c[nf] = a[nf * 16 + l15];
        a2c[nf] = a[F_OUT + nf * 16 + l15];
    }
#pragma unroll
    for (int r = 0; r < 4; ++r) {
        float s1 = 0.f, s2 = 0.f;
#pragma unroll
        for (int nf = 0; nf < 8; ++nf) {
            s1 += acc[nf][r] * a1c[nf];
            s2 += acc[nf][r] * a2c[nf];
        }
        s1 += __shfl_xor(s1, 1, 16);
        s1 += __shfl_xor(s1, 2, 16);
        s1 += __shfl_xor(s1, 4, 16);
        s1 += __shfl_xor(s1, 8, 16);
        s2 += __shfl_xor(s2, 1, 16);
        s2 += __shfl_xor(s2, 2, 16);
        s2 += __shfl_xor(s2, 4, 16);
        s2 += __shfl_xor(s2, 8, 16);
        if (l15 == 0) {
            f1L[rowbase + g * 4 + r] = s1 * LOG2E;
            f2L[rowbase + g * 4 + r] = s2 * LOG2E;
        }
    }
}

// ---------------------------------------------------------------------------
// K2: flash4 — fused adj + masked softmax + PV partials.
// Grid 512 = 64 row-tiles(128) x 8 k-slices(1024); blockIdx&7=ks -> the 256 KB
// B-slice is XCD-local L2-hot. 512 thr, 8 waves; wave = 16 rows x 128 cols x
// 1024 k (32 steps). Per step: lane reads its row's adj 2xint4 (A-frag layout,
// prefetched 2 steps ahead, static parity bufs), exp -> pa, 8 ds_read + 8 MFMA
// (setprio). B staged per 256-k chunk into 64 KB swizzled LDS (raw barriers,
// no vmcnt drain -> adj prefetches survive). f2 slice lives in LDS.
// ---------------------------------------------------------------------------
#define STEP(TT, A0, A1)                                                         \
    do {                                                                         \
        const int aa_[8] = {A0.x, A0.y, A0.z, A0.w, A1.x, A1.y, A1.z, A1.w};     \
        const float4 fa_ = *(const float4*)&f2s[(TT) * 32 + g * 8];              \
        const float4 fb_ = *(const float4*)&f2s[(TT) * 32 + g * 8 + 4];          \
        const float ff_[8] = {fa_.x, fa_.y, fa_.z, fa_.w, fb_.x, fb_.y, fb_.z, fb_.w}; \
        bf16x8 pa_;                                                              \
        _Pragma("unroll") for (int j = 0; j < 8; ++j) {                          \
            const float x_ = f1a + ff_[j];                                       \
            const float e_ = __builtin_amdgcn_exp2f(fmaxf(x_, ALPHA * x_));      \
            pa_[j] = (bf16)(aa_[j] > 0 ? e_ : 0.f);                              \
        }                                                                        \
        _Pragma("unroll") for (int j = 0; j < 8; ++j) rs0 += (float)pa_[j];      \
        {                                                                        \
            const int tn_ = ((TT) + 2 < 32 ? (TT) + 2 : 31) * 32;                \
            A0 = *(const int4*)(arp + tn_);                                      \
            A1 = *(const int4*)(arp + tn_ + 4);                                  \
        }                                                                        \
        __builtin_amdgcn_sched_barrier(0);                                       \
        __builtin_amdgcn_s_setprio(1);                                           \
        _Pragma("unroll") for (int nf = 0; nf < 8; ++nf) {                       \
            const int c_ = nf * 16 + l15;                                        \
            const int off_ = c_ * 512 + ((TT) & 7) * 64 + g * 16;                \
            const bf16x8 bh_ = *(const bf16x8*)(ldsb + (off_ ^ ((c_ & 7) << 4))); \
            acc[nf] = __builtin_amdgcn_mfma_f32_16x16x32_bf16(pa_, bh_, acc[nf], 0, 0, 0); \
        }                                                                        \
        __builtin_amdgcn_s_setprio(0);                                           \
    } while (0)

__global__ __launch_bounds__(512, 4) void gat_flash4(
        const int* __restrict__ adj,
        const bf16* __restrict__ WhT,
        const float* __restrict__ f1L,
        const float* __restrict__ f2L,
        float* __restrict__ O_part,
        float* __restrict__ rs_part) {
    __shared__ bf16 Blds[128 * 256];  // 64 KB
    __shared__ float f2s[1024];       // 4 KB: this ks' f2 slice

    const int tid = threadIdx.x;
    const int wv = tid >> 6;
    const int l = tid & 63;
    const int l15 = l & 15;
    const int g = l >> 4;
    const int rb = blockIdx.x >> 3;
    const int ks = blockIdx.x & 7;
    const int row0 = rb * 128 + wv * 16;

    const float f1a = f1L[row0 + l15];
    const int* arp = adj + (size_t)(row0 + l15) * NN + ks * 1024 + g * 8;
    char* ldsb = (char*)&Blds[0];

    f32x4 acc[8];
    const f32x4 zz = {0.f, 0.f, 0.f, 0.f};
#pragma unroll
    for (int nf = 0; nf < 8; ++nf) acc[nf] = zz;
    float rs0 = 0.f;

    // f2 slice -> LDS (covered by the first stage barrier)
    {
        const float2 v = *(const float2*)(f2L + ks * 1024 + tid * 2);
        *(float2*)&f2s[tid * 2] = v;
    }

    // adj prefetch: steps 0 (E) and 1 (O), issued before anything else global
    int4 aE0 = *(const int4*)(arp);
    int4 aE1 = *(const int4*)(arp + 4);
    int4 aO0 = *(const int4*)(arp + 32);
    int4 aO1 = *(const int4*)(arp + 36);

    for (int c4 = 0; c4 < 4; ++c4) {
        const int kc0 = ks * 1024 + c4 * 256;
        // ---- stage B chunk [128 c][256 k] bf16, XOR-swizzled ----
#pragma unroll
        for (int it = 0; it < 8; ++it) {
            const int idx = it * 512 + tid;
            const int cc = idx >> 5;
            const int ku = idx & 31;
            const bf16x8 v = *(const bf16x8*)(WhT + (size_t)cc * NN + kc0 + ku * 8);
            const int dst = cc * 512 + ku * 16;
            *(bf16x8*)(ldsb + (dst ^ ((cc & 7) << 4))) = v;
        }
        asm volatile("s_waitcnt lgkmcnt(0)" ::: "memory");
        __builtin_amdgcn_s_barrier();
        __builtin_amdgcn_sched_barrier(0);

        const int t0 = c4 * 8;
        STEP(t0 + 0, aE0, aE1);
        STEP(t0 + 1, aO0, aO1);
        STEP(t0 + 2, aE0, aE1);
        STEP(t0 + 3, aO0, aO1);
        STEP(t0 + 4, aE0, aE1);
        STEP(t0 + 5, aO0, aO1);
        STEP(t0 + 6, aE0, aE1);
        STEP(t0 + 7, aO0, aO1);

        // all waves done reading this chunk before it is overwritten
        __builtin_amdgcn_s_barrier();
        __builtin_amdgcn_sched_barrier(0);
    }

    // rowsum partial across the 4 g-groups
    rs0 += __shfl_xor(rs0, 16);
    rs0 += __shfl_xor(rs0, 32);
    if (l < 16) rs_part[(size_t)ks * NN + row0 + l15] = rs0;

    // O partial. D layout (m89): row = 4*(l>>4)+reg, col = l&15.
    float* ob = O_part + ((size_t)ks << 20);
#pragma unroll
    for (int nf = 0; nf < 8; ++nf)
#pragma unroll
        for (int r = 0; r < 4; ++r)
            ob[(size_t)(row0 + g * 4 + r) * F_OUT + nf * 16 + l15] = acc[nf][r];
}

// ---------------------------------------------------------------------------
// K3: reduce k-slices: out = (sum_s O_part[s]) / (sum_s rs_part[s]).
// ---------------------------------------------------------------------------
__global__ __launch_bounds__(256) void gat_reduce(const float* __restrict__ O_part,
                                                  const float* __restrict__ rs_part,
                                                  float* __restrict__ out) {
    const int idx = blockIdx.x * 256 + threadIdx.x;
    const int r = idx >> 5;
    const int c = (idx & 31) * 4;
    float rsum = 0.f;
#pragma unroll
    for (int s = 0; s < KSLICES; ++s) rsum += rs_part[(size_t)s * NN + r];
    float4 o = {0.f, 0.f, 0.f, 0.f};
#pragma unroll
    for (int s = 0; s < KSLICES; ++s) {
        const float4 v = *(const float4*)(O_part + ((size_t)s << 20) + (size_t)r * F_OUT + c);
        o.x += v.x;
        o.y += v.y;
        o.z += v.z;
        o.w += v.w;
    }
    const float inv = 1.0f / rsum;
    o.x *= inv;
    o.y *= inv;
    o.z *= inv;
    o.w *= inv;
    *(float4*)(out + (size_t)r * F_OUT + c) = o;
}

// ---------------------------------------------------------------------------
extern "C" void kernel_launch(void* const* d_in, const int* in_sizes, int n_in,
                              void* d_out, int out_size, void* d_ws, size_t ws_size,
                              hipStream_t stream) {
    const float* h = (const float*)d_in[0];  // (8192, 256) fp32
    const int* adj = (const int*)d_in[1];    // (8192, 8192) int32
    const float* W = (const float*)d_in[2];  // (128, 256) fp32
    const float* a = (const float*)d_in[3];  // (1, 256) fp32
    float* out = (float*)d_out;              // (8192, 128) fp32

    char* ws = (char*)d_ws;
    const size_t MB = 1024 * 1024;
    bf16* WhT = (bf16*)ws;                         // 2 MB
    float* f1L = (float*)(ws + 2 * MB);            // 32 KB
    float* f2L = f1L + NN;                         // 32 KB
    bf16* Whi = (bf16*)(ws + 2 * MB + 64 * 1024);  // 64 KB
    bf16* Wlo = (bf16*)(ws + 2 * MB + 128 * 1024); // 64 KB
    float* rs_part = (float*)(ws + 3 * MB);        // 256 KB
    float* O_part = (float*)(ws + 4 * MB);         // 32 MB

    gat_wsplit<<<128, 256, 0, stream>>>(W, Whi, Wlo);
    gat_wh<<<256, 128, 0, stream>>>(h, Whi, Wlo, a, WhT, f1L, f2L);
    gat_flash4<<<512, 512, 0, stream>>>(adj, WhT, f1L, f2L, O_part, rs_part);
    gat_reduce<<<NN * F_OUT / 4 / 256, 256, 0, stream>>>(O_part, rs_part, out);
}